// Round 1
// 661.674 us; speedup vs baseline: 1.6021x; 1.6021x over previous
//
#include <hip/hip_runtime.h>

// Problem constants
#define B_    1024
#define S_    64
#define D_    768
#define POOL_ 30
#define TOPK_ 4
#define SEQ_  68
#define CT_   64

// d_out element offsets (f32)
#define OUT_NP    50331648ull              // B*CT*D
#define OUT_RSIM  50331648ull
#define OUT_SIM   50331649ull
#define OUT_IDX   50362369ull              // OUT_SIM + B*POOL

typedef short s16x8 __attribute__((ext_vector_type(8)));
typedef float f32x4 __attribute__((ext_vector_type(4)));
typedef unsigned short u16;

__device__ __forceinline__ u16 f2bf(float f){
  unsigned u = __float_as_uint(f);
  u += 0x7fff + ((u >> 16) & 1);           // RNE
  return (u16)(u >> 16);
}

// ---------------------------------------------------------------------------
// K0a: prompt norms + small weights packed into MFMA-fragment order.
// Fragment layout for (nt, ks): element ((nt*KS + ks)*64 + lane)*8 + e holds
//   w[k][n] with k = ks*32 + (lane>>4)*8 + e, n = nt*16 + (lane&15)
// so a wave's b-frag load is one contiguous 1 KB line-friendly read.
// ---------------------------------------------------------------------------
__global__ void prep_small(const float* __restrict__ prompt,
                           const float* __restrict__ w1a,
                           const float* __restrict__ w1b,
                           float* __restrict__ pnorm2,
                           u16* __restrict__ w1aT, u16* __restrict__ w1bT){
  int t = threadIdx.x;
  if (blockIdx.x == 0){
    if (t < 240){
      int j = t >> 3, seg = t & 7;
      float s = 0.f;
      for (int d = seg*96; d < seg*96 + 96; ++d){ float v = prompt[j*768 + d]; s += v*v; }
      #pragma unroll
      for (int m = 1; m < 8; m <<= 1) s += __shfl_xor(s, m);
      if (seg == 0) pnorm2[j] = rsqrtf(fmaxf(s, 1e-12f));
    }
  } else if (blockIdx.x == 1){
    // w1a packed: 4 nt-tiles x 3 ks-tiles (K zero-padded 68->96)
    for (int e = t; e < 6144; e += 256){
      int frag = e >> 3, el = e & 7;
      int lane = frag & 63, tile = frag >> 6;     // tile = nt*3 + ks, [0,12)
      int nt = tile / 3, ks = tile % 3;
      int k  = ks*32 + (lane >> 4)*8 + el;
      int ct = nt*16 + (lane & 15);
      w1aT[e] = f2bf(k < SEQ_ ? w1a[k*64 + ct] : 0.f);
    }
  } else {
    // w1b packed: 4 nt-tiles x 2 ks-tiles
    for (int e = t; e < 4096; e += 256){
      int frag = e >> 3, el = e & 7;
      int lane = frag & 63, tile = frag >> 6;     // tile = nt*2 + ks, [0,8)
      int nt = tile >> 1, ks = tile & 1;
      int k  = ks*32 + (lane >> 4)*8 + el;
      int n  = nt*16 + (lane & 15);
      w1bT[e] = f2bf(w1b[k*64 + n]);
    }
  }
}

// ---------------------------------------------------------------------------
// K0b: pack 768x768 f32 weights into bf16 MFMA-fragment order.
// Wpk element ((ntg*24 + ks)*64 + lane)*8 + e = w[k][n],
//   k = ks*32 + (lane>>4)*8 + e,  n = ntg*16 + (lane&15)
// ---------------------------------------------------------------------------
__global__ void pack_w(const float* __restrict__ w2a,
                       const float* __restrict__ w2b,
                       u16* __restrict__ Wpka, u16* __restrict__ Wpkb){
  int lane = threadIdx.x;                          // 64
  int ntg = blockIdx.x, ks = blockIdx.y;           // 48 x 24
  const float* w = blockIdx.z ? w2b : w2a;
  u16* wp = (blockIdx.z ? Wpkb : Wpka) + ((size_t)(ntg*24 + ks)*64 + lane)*8;
  int n  = ntg*16 + (lane & 15);
  int k0 = ks*32 + (lane >> 4)*8;
  #pragma unroll
  for (int e = 0; e < 8; ++e) wp[e] = f2bf(w[(size_t)(k0 + e)*768 + n]);
}

// ---------------------------------------------------------------------------
// K1: per-batch mean, l2-norm, 30 similarities, top-4, reduce_sim
// ---------------------------------------------------------------------------
__global__ void sim_topk(const float* __restrict__ xe,
                         const float* __restrict__ prompt,
                         const float* __restrict__ pnorm2,
                         float* __restrict__ out, int* __restrict__ idx_int){
  int b = blockIdx.x, t = threadIdx.x;
  int lane = t & 63, wv = t >> 6;
  float xm[3];
  #pragma unroll
  for (int r = 0; r < 3; ++r){
    int d = t + 256*r;
    float a = 0.f;
    for (int s = 0; s < 64; ++s) a += xe[((size_t)b*64 + s)*768 + d];
    xm[r] = a * (1.f/64.f);
  }
  float loc = xm[0]*xm[0] + xm[1]*xm[1] + xm[2]*xm[2];
  #pragma unroll
  for (int m = 1; m < 64; m <<= 1) loc += __shfl_xor(loc, m);

  __shared__ float wred[4];
  __shared__ float rsx_sh;
  __shared__ float wpart[4][30];
  __shared__ float simv[30];
  if (lane == 0) wred[wv] = loc;
  __syncthreads();
  if (t == 0) rsx_sh = rsqrtf(fmaxf(wred[0]+wred[1]+wred[2]+wred[3], 1e-12f));

  float part[30];
  #pragma unroll
  for (int j = 0; j < 30; ++j) part[j] = 0.f;
  #pragma unroll
  for (int j = 0; j < 30; ++j){
    #pragma unroll
    for (int r = 0; r < 3; ++r) part[j] += xm[r] * prompt[j*768 + t + 256*r];
  }
  #pragma unroll
  for (int j = 0; j < 30; ++j){
    float v = part[j];
    #pragma unroll
    for (int m = 1; m < 64; m <<= 1) v += __shfl_xor(v, m);
    if (lane == 0) wpart[wv][j] = v;
  }
  __syncthreads();
  float rsx = rsx_sh;
  if (t < 30){
    float s = wpart[0][t] + wpart[1][t] + wpart[2][t] + wpart[3][t];
    float sim = s * rsx * pnorm2[t];
    out[OUT_SIM + (size_t)b*30 + t] = sim;
    simv[t] = sim;
  }
  __syncthreads();
  if (t == 0){
    float racc = 0.f;
    for (int k = 0; k < 4; ++k){
      float best = -1e30f; int bi = 0;
      for (int j = 0; j < 30; ++j){ float v = simv[j]; if (v > best){ best = v; bi = j; } }
      simv[bi] = -1e30f;
      idx_int[b*4 + k] = bi;
      out[OUT_IDX + (size_t)b*4 + k] = (float)bi;
      racc += best;
    }
    atomicAdd(&out[OUT_RSIM], racc * (1.f/1024.f));
  }
}

// ---------------------------------------------------------------------------
// K2: mlp_1 — per (b, 128-d chunk): T[b*64+ct][d] = LN(relu(LN(relu(X^T w1a + b1a)) w1b + b1b))
// ---------------------------------------------------------------------------
__global__ void stage1(const float* __restrict__ xe, const float* __restrict__ prompt,
                       const int* __restrict__ idx_int,
                       const u16* __restrict__ w1aT, const u16* __restrict__ w1bT,
                       const float* __restrict__ b1a, const float* __restrict__ g1a, const float* __restrict__ be1a,
                       const float* __restrict__ b1b, const float* __restrict__ g1b, const float* __restrict__ be1b,
                       u16* __restrict__ Tg){
  __shared__ __align__(16) unsigned char sm[45056];
  u16 (*As)[104]  = (u16(*)[104])sm;                 // 128 x 104 bf16 (K pad 96, +8 bank pad)
  u16 (*A2s)[72]  = (u16(*)[72])(sm + 26624);        // 128 x 72
  u16 (*Ts)[136]  = (u16(*)[136])sm;                 // 64 x 136 (aliases As)

  int t = threadIdx.x;
  int b = blockIdx.y, d0 = blockIdx.x * 128;
  int dd = t & 127, jr = t >> 7;

  // stage X^T chunk into LDS (bf16), zero-padded K
  #pragma unroll
  for (int p = 0; p < 24; ++p){
    int j = p*4 + jr;
    float v;
    if (j < 4)        v = prompt[(size_t)idx_int[b*4 + j]*768 + d0 + dd];
    else if (j < 68)  v = xe[((size_t)b*64 + (j-4))*768 + d0 + dd];
    else              v = 0.f;
    As[dd][j] = f2bf(v);
  }
  __syncthreads();

  int wv = t >> 6, lane = t & 63, quad = lane >> 4, l15 = lane & 15;
  int mrow = wv*16 + l15;

  // mm1: (128 x 96) @ (96 x 64)  — packed b-frags, coalesced per wave
  f32x4 acc[4];
  #pragma unroll
  for (int nt = 0; nt < 4; ++nt) acc[nt] = (f32x4){0.f,0.f,0.f,0.f};
  #pragma unroll
  for (int ks = 0; ks < 3; ++ks){
    s16x8 a = *(const s16x8*)&As[mrow][ks*32 + quad*8];
    #pragma unroll
    for (int nt = 0; nt < 4; ++nt){
      s16x8 bf = *(const s16x8*)(w1aT + ((nt*3 + ks)*64 + lane)*8);
      acc[nt] = __builtin_amdgcn_mfma_f32_16x16x32_bf16(a, bf, acc[nt], 0, 0, 0);
    }
  }
  // bias + relu + LN(64) — entire row lives in this wave
  {
    float s1[4] = {0,0,0,0}, s2[4] = {0,0,0,0};
    #pragma unroll
    for (int nt = 0; nt < 4; ++nt){
      float bb = b1a[nt*16 + l15];
      #pragma unroll
      for (int i = 0; i < 4; ++i){
        float v = fmaxf(acc[nt][i] + bb, 0.f);
        acc[nt][i] = v; s1[i] += v; s2[i] += v*v;
      }
    }
    #pragma unroll
    for (int i = 0; i < 4; ++i){
      #pragma unroll
      for (int m = 1; m < 16; m <<= 1){ s1[i] += __shfl_xor(s1[i], m); s2[i] += __shfl_xor(s2[i], m); }
    }
    #pragma unroll
    for (int i = 0; i < 4; ++i){
      float mean = s1[i]*(1.f/64.f);
      float var  = s2[i]*(1.f/64.f) - mean*mean;
      float rs   = rsqrtf(var + 1e-5f);
      int row = wv*16 + quad*4 + i;
      #pragma unroll
      for (int nt = 0; nt < 4; ++nt){
        int ct = nt*16 + l15;
        A2s[row][ct] = f2bf((acc[nt][i] - mean)*rs*g1a[ct] + be1a[ct]);
      }
    }
  }
  __syncthreads();

  // mm2: (128 x 64) @ (64 x 64)
  f32x4 acc2[4];
  #pragma unroll
  for (int nt = 0; nt < 4; ++nt) acc2[nt] = (f32x4){0.f,0.f,0.f,0.f};
  #pragma unroll
  for (int ks = 0; ks < 2; ++ks){
    s16x8 a = *(const s16x8*)&A2s[mrow][ks*32 + quad*8];
    #pragma unroll
    for (int nt = 0; nt < 4; ++nt){
      s16x8 bf = *(const s16x8*)(w1bT + ((nt*2 + ks)*64 + lane)*8);
      acc2[nt] = __builtin_amdgcn_mfma_f32_16x16x32_bf16(a, bf, acc2[nt], 0, 0, 0);
    }
  }
  {
    float s1[4] = {0,0,0,0}, s2[4] = {0,0,0,0};
    #pragma unroll
    for (int nt = 0; nt < 4; ++nt){
      float bb = b1b[nt*16 + l15];
      #pragma unroll
      for (int i = 0; i < 4; ++i){
        float v = fmaxf(acc2[nt][i] + bb, 0.f);
        acc2[nt][i] = v; s1[i] += v; s2[i] += v*v;
      }
    }
    #pragma unroll
    for (int i = 0; i < 4; ++i){
      #pragma unroll
      for (int m = 1; m < 16; m <<= 1){ s1[i] += __shfl_xor(s1[i], m); s2[i] += __shfl_xor(s2[i], m); }
    }
    #pragma unroll
    for (int i = 0; i < 4; ++i){
      float mean = s1[i]*(1.f/64.f);
      float var  = s2[i]*(1.f/64.f) - mean*mean;
      float rs   = rsqrtf(var + 1e-5f);
      int row = wv*16 + quad*4 + i;
      #pragma unroll
      for (int nt = 0; nt < 4; ++nt){
        int ct = nt*16 + l15;
        Ts[ct][row] = f2bf((acc2[nt][i] - mean)*rs*g1b[ct] + be1b[ct]);   // transposed: [ct][d]
      }
    }
  }
  __syncthreads();

  // coalesced bf16 write: T[(b*64+ct)][d0..d0+127]
  #pragma unroll
  for (int c = t; c < 1024; c += 512){
    int ct = c >> 4, off = (c & 15)*8;
    *(s16x8*)(Tg + ((size_t)(b*64 + ct))*768 + d0 + off) = *(const s16x8*)&Ts[ct][off];
  }
}

// ---------------------------------------------------------------------------
// K3: mlp_2 — 64 rows x (N=768, K=768) per block, fused GEMM+LN twice.
// 8 waves: wave wv owns ALL 64 rows x cols [wv*96, wv*96+96).
//   - B operand pre-packed in fragment order: each b-frag load is one
//     contiguous, fully-coalesced 1 KB wave read (was 16 quarter-used
//     cache lines at row-stride 1536 B -> TA line-rate bound, MfmaUtil 11%)
//   - M=64 rows/block halves total WT L2 traffic (4.8 GB -> 2.4 GB) and
//     doubles MFMA work per loaded B-byte (24 MFMA per k-step per wave)
//   - __launch_bounds__(512,2): 256-reg budget, 1 block/CU (LDS 99 KB);
//     latency cover = 24 MFMA x ~5cyc x 2 waves/SIMD >= L2 hit latency
// ---------------------------------------------------------------------------
__device__ __forceinline__ void gemm_ln_768(
    const u16* __restrict__ Wpk, const float* __restrict__ bias,
    const float* __restrict__ g, const float* __restrict__ be,
    u16 (*Arows)[776], float (*red)[64][8], float (*redt)[64],
    float* __restrict__ outp, int row0, int t, bool final_store)
{
  int wv = t >> 6, lane = t & 63, quad = lane >> 4, l15 = lane & 15;
  f32x4 acc[4][6];
  #pragma unroll
  for (int mt = 0; mt < 4; ++mt)
    #pragma unroll
    for (int nt = 0; nt < 6; ++nt) acc[mt][nt] = (f32x4){0.f,0.f,0.f,0.f};

  // wave's packed-weight base: col-tiles ntg = wv*6 + nt; frag (nt,ks) at
  // wbase + nt*12288 + ks*512 (u16 elements), contiguous 1 KB per wave-read
  const u16* wbase = Wpk + (size_t)wv*73728 + (size_t)lane*8;

  s16x8 bnxt[6];
  #pragma unroll
  for (int nt = 0; nt < 6; ++nt)
    bnxt[nt] = *(const s16x8*)(wbase + nt*12288);

  #pragma unroll
  for (int ks = 0; ks < 24; ++ks){
    s16x8 bcur[6];
    #pragma unroll
    for (int nt = 0; nt < 6; ++nt) bcur[nt] = bnxt[nt];
    if (ks < 23){
      #pragma unroll
      for (int nt = 0; nt < 6; ++nt)
        bnxt[nt] = *(const s16x8*)(wbase + nt*12288 + (ks+1)*512);
    }
    s16x8 a[4];
    #pragma unroll
    for (int mt = 0; mt < 4; ++mt)
      a[mt] = *(const s16x8*)&Arows[mt*16 + l15][ks*32 + quad*8];
    #pragma unroll
    for (int nt = 0; nt < 6; ++nt){
      #pragma unroll
      for (int mt = 0; mt < 4; ++mt)
        acc[mt][nt] = __builtin_amdgcn_mfma_f32_16x16x32_bf16(a[mt], bcur[nt], acc[mt][nt], 0, 0, 0);
    }
  }

  // bias + relu + per-row partial LN sums (this wave covers 96 of 768 cols)
  float s1[4][4], s2[4][4];
  #pragma unroll
  for (int mt = 0; mt < 4; ++mt)
    #pragma unroll
    for (int i = 0; i < 4; ++i){ s1[mt][i] = 0.f; s2[mt][i] = 0.f; }
  #pragma unroll
  for (int nt = 0; nt < 6; ++nt){
    float bb = bias[wv*96 + nt*16 + l15];
    #pragma unroll
    for (int mt = 0; mt < 4; ++mt){
      #pragma unroll
      for (int i = 0; i < 4; ++i){
        float v = fmaxf(acc[mt][nt][i] + bb, 0.f);
        acc[mt][nt][i] = v; s1[mt][i] += v; s2[mt][i] += v*v;
      }
    }
  }
  #pragma unroll
  for (int mt = 0; mt < 4; ++mt){
    #pragma unroll
    for (int i = 0; i < 4; ++i){
      #pragma unroll
      for (int m = 1; m < 16; m <<= 1){
        s1[mt][i] += __shfl_xor(s1[mt][i], m);
        s2[mt][i] += __shfl_xor(s2[mt][i], m);
      }
    }
  }
  if (l15 == 0){
    #pragma unroll
    for (int mt = 0; mt < 4; ++mt)
      #pragma unroll
      for (int i = 0; i < 4; ++i){
        int row = mt*16 + quad*4 + i;
        red[0][row][wv] = s1[mt][i]; red[1][row][wv] = s2[mt][i];
      }
  }
  __syncthreads();
  if (t < 128){
    int r = t >> 1, p = t & 1;
    float s = 0.f;
    #pragma unroll
    for (int w = 0; w < 8; ++w) s += red[p][r][w];
    redt[p][r] = s;
  }
  __syncthreads();
  #pragma unroll
  for (int mt = 0; mt < 4; ++mt){
    #pragma unroll
    for (int i = 0; i < 4; ++i){
      int row = mt*16 + quad*4 + i;
      float mean = redt[0][row]*(1.f/768.f);
      float var  = redt[1][row]*(1.f/768.f) - mean*mean;
      float rs   = rsqrtf(var + 1e-5f);
      #pragma unroll
      for (int nt = 0; nt < 6; ++nt){
        int col = wv*96 + nt*16 + l15;
        float v = (acc[mt][nt][i] - mean)*rs*g[col] + be[col];
        if (final_store) outp[(size_t)(row0 + row)*768 + col] = v;
        else             Arows[row][col] = f2bf(v);
      }
    }
  }
}

__global__ __launch_bounds__(512, 2)
void stage2(const u16* __restrict__ Tg,
            const u16* __restrict__ Wpka, const u16* __restrict__ Wpkb,
            const float* __restrict__ b2a, const float* __restrict__ g2a, const float* __restrict__ be2a,
            const float* __restrict__ b2b, const float* __restrict__ g2b, const float* __restrict__ be2b,
            float* __restrict__ out){
  __shared__ __align__(16) u16 Arows[64][776];   // 99328 B
  __shared__ float red[2][64][8];
  __shared__ float redt[2][64];
  int t = threadIdx.x;
  int row0 = blockIdx.x * 64;
  #pragma unroll
  for (int c = t; c < 6144; c += 512){
    int r = c / 96, off = (c % 96)*8;
    *(s16x8*)&Arows[r][off] = *(const s16x8*)(Tg + (size_t)(row0 + r)*768 + off);
  }
  __syncthreads();
  gemm_ln_768(Wpka, b2a, g2a, be2a, Arows, red, redt, out, row0, t, false);
  __syncthreads();
  gemm_ln_768(Wpkb, b2b, g2b, be2b, Arows, red, redt, out, row0, t, true);
}

// ---------------------------------------------------------------------------
extern "C" void kernel_launch(void* const* d_in, const int* in_sizes, int n_in,
                              void* d_out, int out_size, void* d_ws, size_t ws_size,
                              hipStream_t stream){
  (void)in_sizes; (void)n_in; (void)out_size; (void)ws_size;
  const float* xe     = (const float*)d_in[0];
  const float* prompt = (const float*)d_in[1];
  const float* w1a = (const float*)d_in[2],  *b1a = (const float*)d_in[3];
  const float* g1a = (const float*)d_in[4],  *be1a= (const float*)d_in[5];
  const float* w1b = (const float*)d_in[6],  *b1b = (const float*)d_in[7];
  const float* g1b = (const float*)d_in[8],  *be1b= (const float*)d_in[9];
  const float* w2a = (const float*)d_in[10], *b2a = (const float*)d_in[11];
  const float* g2a = (const float*)d_in[12], *be2a= (const float*)d_in[13];
  const float* w2b = (const float*)d_in[14], *b2b = (const float*)d_in[15];
  const float* g2b = (const float*)d_in[16], *be2b= (const float*)d_in[17];
  float* out = (float*)d_out;

  char* ws = (char*)d_ws;
  u16*   Tg     = (u16*)(ws);                      // 65536 x 768 bf16 = 100663296 B
  u16*   Wpka   = (u16*)(ws + 100663296);          // 768x768 bf16 (packed frag order)
  u16*   Wpkb   = (u16*)(ws + 101842944);
  u16*   w1aT   = (u16*)(ws + 103022592);          // 64x96 bf16 (packed)
  u16*   w1bT   = (u16*)(ws + 103034880);          // 64x64 bf16 (packed)
  float* pnorm2 = (float*)(ws + 103043072);        // 30 f32
  int*   idx_i  = (int*)(ws + 103043200);          // B*4 int

  hipMemsetAsync((char*)d_out + OUT_RSIM*sizeof(float), 0, sizeof(float), stream);
  prep_small<<<3, 256, 0, stream>>>(prompt, w1a, w1b, pnorm2, w1aT, w1bT);
  pack_w<<<dim3(48,24,2), 64, 0, stream>>>(w2a, w2b, Wpka, Wpkb);
  sim_topk<<<B_, 256, 0, stream>>>(xe, prompt, pnorm2, out, idx_i);
  stage1<<<dim3(6, B_), 512, 0, stream>>>(xe, prompt, idx_i, w1aT, w1bT,
                                          b1a, g1a, be1a, b1b, g1b, be1b, Tg);
  stage2<<<1024, 512, 0, stream>>>(Tg, Wpka, Wpkb, b2a, g2a, be2a, b2b, g2b, be2b, out);
}

// Round 2
// 637.510 us; speedup vs baseline: 1.6628x; 1.0379x over previous
//
#include <hip/hip_runtime.h>

// Problem constants
#define B_    1024
#define S_    64
#define D_    768
#define POOL_ 30
#define TOPK_ 4
#define SEQ_  68
#define CT_   64

// d_out element offsets (f32)
#define OUT_NP    50331648ull              // B*CT*D
#define OUT_RSIM  50331648ull
#define OUT_SIM   50331649ull
#define OUT_IDX   50362369ull              // OUT_SIM + B*POOL

typedef short s16x8 __attribute__((ext_vector_type(8)));
typedef float f32x4 __attribute__((ext_vector_type(4)));
typedef unsigned short u16;

__device__ __forceinline__ u16 f2bf(float f){
  unsigned u = __float_as_uint(f);
  u += 0x7fff + ((u >> 16) & 1);           // RNE
  return (u16)(u >> 16);
}

// ---------------------------------------------------------------------------
// K0a: prompt norms + small weights packed into MFMA-fragment order.
// Fragment layout for (nt, ks): element ((nt*KS + ks)*64 + lane)*8 + e holds
//   w[k][n] with k = ks*32 + (lane>>4)*8 + e, n = nt*16 + (lane&15)
// ---------------------------------------------------------------------------
__global__ void prep_small(const float* __restrict__ prompt,
                           const float* __restrict__ w1a,
                           const float* __restrict__ w1b,
                           float* __restrict__ pnorm2,
                           u16* __restrict__ w1aT, u16* __restrict__ w1bT){
  int t = threadIdx.x;
  if (blockIdx.x == 0){
    if (t < 240){
      int j = t >> 3, seg = t & 7;
      float s = 0.f;
      for (int d = seg*96; d < seg*96 + 96; ++d){ float v = prompt[j*768 + d]; s += v*v; }
      #pragma unroll
      for (int m = 1; m < 8; m <<= 1) s += __shfl_xor(s, m);
      if (seg == 0) pnorm2[j] = rsqrtf(fmaxf(s, 1e-12f));
    }
  } else if (blockIdx.x == 1){
    // w1a packed: 4 nt-tiles x 3 ks-tiles (K zero-padded 68->96)
    for (int e = t; e < 6144; e += 256){
      int frag = e >> 3, el = e & 7;
      int lane = frag & 63, tile = frag >> 6;     // tile = nt*3 + ks, [0,12)
      int nt = tile / 3, ks = tile % 3;
      int k  = ks*32 + (lane >> 4)*8 + el;
      int ct = nt*16 + (lane & 15);
      w1aT[e] = f2bf(k < SEQ_ ? w1a[k*64 + ct] : 0.f);
    }
  } else {
    // w1b packed: 4 nt-tiles x 2 ks-tiles
    for (int e = t; e < 4096; e += 256){
      int frag = e >> 3, el = e & 7;
      int lane = frag & 63, tile = frag >> 6;     // tile = nt*2 + ks, [0,8)
      int nt = tile >> 1, ks = tile & 1;
      int k  = ks*32 + (lane >> 4)*8 + el;
      int n  = nt*16 + (lane & 15);
      w1bT[e] = f2bf(w1b[k*64 + n]);
    }
  }
}

// ---------------------------------------------------------------------------
// K0b: pack 768x768 f32 weights into bf16 MFMA-fragment order.
// Wpk element ((ntg*24 + ks)*64 + lane)*8 + e = w[k][n],
//   k = ks*32 + (lane>>4)*8 + e,  n = ntg*16 + (lane&15)
// ---------------------------------------------------------------------------
__global__ void pack_w(const float* __restrict__ w2a,
                       const float* __restrict__ w2b,
                       u16* __restrict__ Wpka, u16* __restrict__ Wpkb){
  int lane = threadIdx.x;                          // 64
  int ntg = blockIdx.x, ks = blockIdx.y;           // 48 x 24
  const float* w = blockIdx.z ? w2b : w2a;
  u16* wp = (blockIdx.z ? Wpkb : Wpka) + ((size_t)(ntg*24 + ks)*64 + lane)*8;
  int n  = ntg*16 + (lane & 15);
  int k0 = ks*32 + (lane >> 4)*8;
  #pragma unroll
  for (int e = 0; e < 8; ++e) wp[e] = f2bf(w[(size_t)(k0 + e)*768 + n]);
}

// ---------------------------------------------------------------------------
// K1: per-batch mean, l2-norm, 30 similarities, top-4, reduce_sim
// Fully vectorized: float4 loads everywhere, wave-parallel reductions.
// ---------------------------------------------------------------------------
__global__ void sim_topk(const float* __restrict__ xe,
                         const float* __restrict__ prompt,
                         const float* __restrict__ pnorm2,
                         float* __restrict__ out, int* __restrict__ idx_int){
  __shared__ f32x4 ps[4][192];       // per-wave partial row-sums (12.3 KB)
  __shared__ f32x4 xm4s[192];        // mean vector (3 KB)
  __shared__ float wred[4];
  __shared__ float rsx_sh;
  __shared__ float simv[30];
  int b = blockIdx.x, t = threadIdx.x;
  int lane = t & 63, wv = t >> 6;

  // phase 1: wave wv sums rows s = wv*16 .. wv*16+15 (vectorized 16B loads)
  const f32x4* xrow = (const f32x4*)(xe + (size_t)b*64*768);
  f32x4 a0 = {0.f,0.f,0.f,0.f}, a1 = a0, a2 = a0;
  #pragma unroll
  for (int r = 0; r < 16; ++r){
    const f32x4* rp = xrow + (size_t)(wv*16 + r)*192;
    a0 += rp[lane]; a1 += rp[lane + 64]; a2 += rp[lane + 128];
  }
  ps[wv][lane] = a0; ps[wv][lane + 64] = a1; ps[wv][lane + 128] = a2;
  __syncthreads();

  // phase 2: final mean
  if (t < 192){
    f32x4 s = ps[0][t] + ps[1][t] + ps[2][t] + ps[3][t];
    s *= (1.f/64.f);
    xm4s[t] = s;
  }
  __syncthreads();

  // phase 3: ||xm||^2 (wave 0)
  if (wv == 0){
    f32x4 v0 = xm4s[lane], v1 = xm4s[lane + 64], v2 = xm4s[lane + 128];
    float n = v0[0]*v0[0]+v0[1]*v0[1]+v0[2]*v0[2]+v0[3]*v0[3]
            + v1[0]*v1[0]+v1[1]*v1[1]+v1[2]*v1[2]+v1[3]*v1[3]
            + v2[0]*v2[0]+v2[1]*v2[1]+v2[2]*v2[2]+v2[3]*v2[3];
    #pragma unroll
    for (int m = 1; m < 64; m <<= 1) n += __shfl_xor(n, m);
    if (lane == 0) rsx_sh = rsqrtf(fmaxf(n, 1e-12f));
  }
  __syncthreads();

  // phase 4: 30 similarities, 8 threads per prompt (96 d each, float4)
  if (t < 240){
    int j = t >> 3, seg = t & 7;
    const f32x4* pj = (const f32x4*)(prompt + j*768) + seg*24;
    const f32x4* xm = xm4s + seg*24;
    float s = 0.f;
    #pragma unroll
    for (int i = 0; i < 24; ++i){
      f32x4 p = pj[i], x = xm[i];
      s += p[0]*x[0] + p[1]*x[1] + p[2]*x[2] + p[3]*x[3];
    }
    #pragma unroll
    for (int m = 1; m < 8; m <<= 1) s += __shfl_xor(s, m);
    if (seg == 0){
      float sim = s * rsx_sh * pnorm2[j];
      out[OUT_SIM + (size_t)b*30 + j] = sim;
      simv[j] = sim;
    }
  }
  __syncthreads();

  // phase 5: serial top-4 (tiny; keeps exact tie semantics)
  if (t == 0){
    float racc = 0.f;
    for (int k = 0; k < 4; ++k){
      float best = -1e30f; int bi = 0;
      for (int j = 0; j < 30; ++j){ float v = simv[j]; if (v > best){ best = v; bi = j; } }
      simv[bi] = -1e30f;
      idx_int[b*4 + k] = bi;
      out[OUT_IDX + (size_t)b*4 + k] = (float)bi;
      racc += best;
    }
    atomicAdd(&out[OUT_RSIM], racc * (1.f/1024.f));
  }
}

// ---------------------------------------------------------------------------
// K2: mlp_1 — per (b, 128-d chunk): T[b*64+ct][d] = LN(relu(LN(relu(X^T w1a + b1a)) w1b + b1b))
// X^T staged DIRECTLY into MFMA-fragment-packed LDS:
//   frag (dt, ks) at dt*1544 + ks*512 (u16), element lane*8+e = X^T[d][j],
//   d = dt*16 + (lane&15), j = ks*32 + (lane>>4)*8 + e.
//   -> mm1 A-reads are contiguous conflict-free ds_read_b128 per wave.
// Staging writes pack row-pairs (j, j+1) into one u32 (12 b32 stores/thread,
// half the count of the previous 24 conflicted b16 stores).
// ---------------------------------------------------------------------------
__global__ void stage1(const float* __restrict__ xe, const float* __restrict__ prompt,
                       const int* __restrict__ idx_int,
                       const u16* __restrict__ w1aT, const u16* __restrict__ w1bT,
                       const float* __restrict__ b1a, const float* __restrict__ g1a, const float* __restrict__ be1a,
                       const float* __restrict__ b1b, const float* __restrict__ g1b, const float* __restrict__ be1b,
                       u16* __restrict__ Tg){
  __shared__ __align__(16) unsigned char sm[43136];
  u16* As_pk      = (u16*)sm;                        // 8 dt x (3*512+8) u16 = 24704 B
  u16 (*A2s)[72]  = (u16(*)[72])(sm + 24704);        // 128 x 72 = 18432 B
  u16 (*Ts)[136]  = (u16(*)[136])sm;                 // 64 x 136 (aliases As_pk)

  int t = threadIdx.x;
  int b = blockIdx.y, d0 = blockIdx.x * 128;

  // stage X^T chunk into fragment-packed LDS (bf16), K zero-padded 68->96
  #pragma unroll
  for (int p = 0; p < 12; ++p){
    int item = t + 512*p;                  // 0..6143 = 48 jp x 128 dd
    int dd = item & 127, jp = item >> 7;
    int j = jp << 1;                       // even; pair (j, j+1) same quad/ks
    float v0 = 0.f, v1 = 0.f;
    if (j < 4){
      v0 = prompt[(size_t)idx_int[b*4 + j    ]*768 + d0 + dd];
      v1 = prompt[(size_t)idx_int[b*4 + j + 1]*768 + d0 + dd];
    } else if (j < 68){                    // j in [4,66] even -> j+1 <= 67 valid
      const float* xp = xe + ((size_t)b*64 + (j-4))*768 + d0 + dd;
      v0 = xp[0];
      v1 = xp[768];
    }
    unsigned pk = (unsigned)f2bf(v0) | ((unsigned)f2bf(v1) << 16);
    int idx16 = (dd>>4)*1544 + (j>>5)*512 + ((j>>3)&3)*128 + (dd&15)*8 + (j&7);
    *(unsigned*)&As_pk[idx16] = pk;
  }
  __syncthreads();

  int wv = t >> 6, lane = t & 63, quad = lane >> 4, l15 = lane & 15;
  int mrow = wv*16 + l15;

  // mm1: (128 x 96) @ (96 x 64) — both operands fragment-packed
  f32x4 acc[4];
  #pragma unroll
  for (int nt = 0; nt < 4; ++nt) acc[nt] = (f32x4){0.f,0.f,0.f,0.f};
  #pragma unroll
  for (int ks = 0; ks < 3; ++ks){
    s16x8 a = *(const s16x8*)&As_pk[wv*1544 + ks*512 + lane*8];
    #pragma unroll
    for (int nt = 0; nt < 4; ++nt){
      s16x8 bf = *(const s16x8*)(w1aT + ((nt*3 + ks)*64 + lane)*8);
      acc[nt] = __builtin_amdgcn_mfma_f32_16x16x32_bf16(a, bf, acc[nt], 0, 0, 0);
    }
  }
  // bias + relu + LN(64) — entire row lives in this wave
  {
    float s1[4] = {0,0,0,0}, s2[4] = {0,0,0,0};
    #pragma unroll
    for (int nt = 0; nt < 4; ++nt){
      float bb = b1a[nt*16 + l15];
      #pragma unroll
      for (int i = 0; i < 4; ++i){
        float v = fmaxf(acc[nt][i] + bb, 0.f);
        acc[nt][i] = v; s1[i] += v; s2[i] += v*v;
      }
    }
    #pragma unroll
    for (int i = 0; i < 4; ++i){
      #pragma unroll
      for (int m = 1; m < 16; m <<= 1){ s1[i] += __shfl_xor(s1[i], m); s2[i] += __shfl_xor(s2[i], m); }
    }
    #pragma unroll
    for (int i = 0; i < 4; ++i){
      float mean = s1[i]*(1.f/64.f);
      float var  = s2[i]*(1.f/64.f) - mean*mean;
      float rs   = rsqrtf(var + 1e-5f);
      int row = wv*16 + quad*4 + i;
      #pragma unroll
      for (int nt = 0; nt < 4; ++nt){
        int ct = nt*16 + l15;
        A2s[row][ct] = f2bf((acc[nt][i] - mean)*rs*g1a[ct] + be1a[ct]);
      }
    }
  }
  __syncthreads();

  // mm2: (128 x 64) @ (64 x 64)
  f32x4 acc2[4];
  #pragma unroll
  for (int nt = 0; nt < 4; ++nt) acc2[nt] = (f32x4){0.f,0.f,0.f,0.f};
  #pragma unroll
  for (int ks = 0; ks < 2; ++ks){
    s16x8 a = *(const s16x8*)&A2s[mrow][ks*32 + quad*8];
    #pragma unroll
    for (int nt = 0; nt < 4; ++nt){
      s16x8 bf = *(const s16x8*)(w1bT + ((nt*2 + ks)*64 + lane)*8);
      acc2[nt] = __builtin_amdgcn_mfma_f32_16x16x32_bf16(a, bf, acc2[nt], 0, 0, 0);
    }
  }
  {
    float s1[4] = {0,0,0,0}, s2[4] = {0,0,0,0};
    #pragma unroll
    for (int nt = 0; nt < 4; ++nt){
      float bb = b1b[nt*16 + l15];
      #pragma unroll
      for (int i = 0; i < 4; ++i){
        float v = fmaxf(acc2[nt][i] + bb, 0.f);
        acc2[nt][i] = v; s1[i] += v; s2[i] += v*v;
      }
    }
    #pragma unroll
    for (int i = 0; i < 4; ++i){
      #pragma unroll
      for (int m = 1; m < 16; m <<= 1){ s1[i] += __shfl_xor(s1[i], m); s2[i] += __shfl_xor(s2[i], m); }
    }
    #pragma unroll
    for (int i = 0; i < 4; ++i){
      float mean = s1[i]*(1.f/64.f);
      float var  = s2[i]*(1.f/64.f) - mean*mean;
      float rs   = rsqrtf(var + 1e-5f);
      int row = wv*16 + quad*4 + i;
      #pragma unroll
      for (int nt = 0; nt < 4; ++nt){
        int ct = nt*16 + l15;
        Ts[ct][row] = f2bf((acc2[nt][i] - mean)*rs*g1b[ct] + be1b[ct]);   // transposed: [ct][d]
      }
    }
  }
  __syncthreads();

  // coalesced bf16 write: T[(b*64+ct)][d0..d0+127]
  #pragma unroll
  for (int c = t; c < 1024; c += 512){
    int ct = c >> 4, off = (c & 15)*8;
    *(s16x8*)(Tg + ((size_t)(b*64 + ct))*768 + d0 + off) = *(const s16x8*)&Ts[ct][off];
  }
}

// ---------------------------------------------------------------------------
// K3: mlp_2 — 64 rows x (N=768, K=768) per block, fused GEMM+LN twice.
// (unchanged from previous round — co-bound on MFMA issue + L2 weight BW)
// ---------------------------------------------------------------------------
__device__ __forceinline__ void gemm_ln_768(
    const u16* __restrict__ Wpk, const float* __restrict__ bias,
    const float* __restrict__ g, const float* __restrict__ be,
    u16 (*Arows)[776], float (*red)[64][8], float (*redt)[64],
    float* __restrict__ outp, int row0, int t, bool final_store)
{
  int wv = t >> 6, lane = t & 63, quad = lane >> 4, l15 = lane & 15;
  f32x4 acc[4][6];
  #pragma unroll
  for (int mt = 0; mt < 4; ++mt)
    #pragma unroll
    for (int nt = 0; nt < 6; ++nt) acc[mt][nt] = (f32x4){0.f,0.f,0.f,0.f};

  const u16* wbase = Wpk + (size_t)wv*73728 + (size_t)lane*8;

  s16x8 bnxt[6];
  #pragma unroll
  for (int nt = 0; nt < 6; ++nt)
    bnxt[nt] = *(const s16x8*)(wbase + nt*12288);

  #pragma unroll
  for (int ks = 0; ks < 24; ++ks){
    s16x8 bcur[6];
    #pragma unroll
    for (int nt = 0; nt < 6; ++nt) bcur[nt] = bnxt[nt];
    if (ks < 23){
      #pragma unroll
      for (int nt = 0; nt < 6; ++nt)
        bnxt[nt] = *(const s16x8*)(wbase + nt*12288 + (ks+1)*512);
    }
    s16x8 a[4];
    #pragma unroll
    for (int mt = 0; mt < 4; ++mt)
      a[mt] = *(const s16x8*)&Arows[mt*16 + l15][ks*32 + quad*8];
    #pragma unroll
    for (int nt = 0; nt < 6; ++nt){
      #pragma unroll
      for (int mt = 0; mt < 4; ++mt)
        acc[mt][nt] = __builtin_amdgcn_mfma_f32_16x16x32_bf16(a[mt], bcur[nt], acc[mt][nt], 0, 0, 0);
    }
  }

  float s1[4][4], s2[4][4];
  #pragma unroll
  for (int mt = 0; mt < 4; ++mt)
    #pragma unroll
    for (int i = 0; i < 4; ++i){ s1[mt][i] = 0.f; s2[mt][i] = 0.f; }
  #pragma unroll
  for (int nt = 0; nt < 6; ++nt){
    float bb = bias[wv*96 + nt*16 + l15];
    #pragma unroll
    for (int mt = 0; mt < 4; ++mt){
      #pragma unroll
      for (int i = 0; i < 4; ++i){
        float v = fmaxf(acc[mt][nt][i] + bb, 0.f);
        acc[mt][nt][i] = v; s1[mt][i] += v; s2[mt][i] += v*v;
      }
    }
  }
  #pragma unroll
  for (int mt = 0; mt < 4; ++mt){
    #pragma unroll
    for (int i = 0; i < 4; ++i){
      #pragma unroll
      for (int m = 1; m < 16; m <<= 1){
        s1[mt][i] += __shfl_xor(s1[mt][i], m);
        s2[mt][i] += __shfl_xor(s2[mt][i], m);
      }
    }
  }
  if (l15 == 0){
    #pragma unroll
    for (int mt = 0; mt < 4; ++mt)
      #pragma unroll
      for (int i = 0; i < 4; ++i){
        int row = mt*16 + quad*4 + i;
        red[0][row][wv] = s1[mt][i]; red[1][row][wv] = s2[mt][i];
      }
  }
  __syncthreads();
  if (t < 128){
    int r = t >> 1, p = t & 1;
    float s = 0.f;
    #pragma unroll
    for (int w = 0; w < 8; ++w) s += red[p][r][w];
    redt[p][r] = s;
  }
  __syncthreads();
  #pragma unroll
  for (int mt = 0; mt < 4; ++mt){
    #pragma unroll
    for (int i = 0; i < 4; ++i){
      int row = mt*16 + quad*4 + i;
      float mean = redt[0][row]*(1.f/768.f);
      float var  = redt[1][row]*(1.f/768.f) - mean*mean;
      float rs   = rsqrtf(var + 1e-5f);
      #pragma unroll
      for (int nt = 0; nt < 6; ++nt){
        int col = wv*96 + nt*16 + l15;
        float v = (acc[mt][nt][i] - mean)*rs*g[col] + be[col];
        if (final_store) outp[(size_t)(row0 + row)*768 + col] = v;
        else             Arows[row][col] = f2bf(v);
      }
    }
  }
}

__global__ __launch_bounds__(512, 2)
void stage2(const u16* __restrict__ Tg,
            const u16* __restrict__ Wpka, const u16* __restrict__ Wpkb,
            const float* __restrict__ b2a, const float* __restrict__ g2a, const float* __restrict__ be2a,
            const float* __restrict__ b2b, const float* __restrict__ g2b, const float* __restrict__ be2b,
            float* __restrict__ out){
  __shared__ __align__(16) u16 Arows[64][776];   // 99328 B
  __shared__ float red[2][64][8];
  __shared__ float redt[2][64];
  int t = threadIdx.x;
  int row0 = blockIdx.x * 64;
  #pragma unroll
  for (int c = t; c < 6144; c += 512){
    int r = c / 96, off = (c % 96)*8;
    *(s16x8*)&Arows[r][off] = *(const s16x8*)(Tg + (size_t)(row0 + r)*768 + off);
  }
  __syncthreads();
  gemm_ln_768(Wpka, b2a, g2a, be2a, Arows, red, redt, out, row0, t, false);
  __syncthreads();
  gemm_ln_768(Wpkb, b2b, g2b, be2b, Arows, red, redt, out, row0, t, true);
}

// ---------------------------------------------------------------------------
extern "C" void kernel_launch(void* const* d_in, const int* in_sizes, int n_in,
                              void* d_out, int out_size, void* d_ws, size_t ws_size,
                              hipStream_t stream){
  (void)in_sizes; (void)n_in; (void)out_size; (void)ws_size;
  const float* xe     = (const float*)d_in[0];
  const float* prompt = (const float*)d_in[1];
  const float* w1a = (const float*)d_in[2],  *b1a = (const float*)d_in[3];
  const float* g1a = (const float*)d_in[4],  *be1a= (const float*)d_in[5];
  const float* w1b = (const float*)d_in[6],  *b1b = (const float*)d_in[7];
  const float* g1b = (const float*)d_in[8],  *be1b= (const float*)d_in[9];
  const float* w2a = (const float*)d_in[10], *b2a = (const float*)d_in[11];
  const float* g2a = (const float*)d_in[12], *be2a= (const float*)d_in[13];
  const float* w2b = (const float*)d_in[14], *b2b = (const float*)d_in[15];
  const float* g2b = (const float*)d_in[16], *be2b= (const float*)d_in[17];
  float* out = (float*)d_out;

  char* ws = (char*)d_ws;
  u16*   Tg     = (u16*)(ws);                      // 65536 x 768 bf16 = 100663296 B
  u16*   Wpka   = (u16*)(ws + 100663296);          // 768x768 bf16 (packed frag order)
  u16*   Wpkb   = (u16*)(ws + 101842944);
  u16*   w1aT   = (u16*)(ws + 103022592);          // 64x96 bf16 (packed)
  u16*   w1bT   = (u16*)(ws + 103034880);          // 64x64 bf16 (packed)
  float* pnorm2 = (float*)(ws + 103043072);        // 30 f32
  int*   idx_i  = (int*)(ws + 103043200);          // B*4 int

  hipMemsetAsync((char*)d_out + OUT_RSIM*sizeof(float), 0, sizeof(float), stream);
  prep_small<<<3, 256, 0, stream>>>(prompt, w1a, w1b, pnorm2, w1aT, w1bT);
  pack_w<<<dim3(48,24,2), 64, 0, stream>>>(w2a, w2b, Wpka, Wpkb);
  sim_topk<<<B_, 256, 0, stream>>>(xe, prompt, pnorm2, out, idx_i);
  stage1<<<dim3(6, B_), 512, 0, stream>>>(xe, prompt, idx_i, w1aT, w1bT,
                                          b1a, g1a, be1a, b1b, g1b, be1b, Tg);
  stage2<<<1024, 512, 0, stream>>>(Tg, Wpka, Wpkb, b2a, g2a, be2a, b2b, g2b, be2b, out);
}